// Round 2
// baseline (520.256 us; speedup 1.0000x reference)
//
#include <hip/hip_runtime.h>
#include <hip/hip_bf16.h>

#define N_NODES 50000
#define N_EDGES 1600000
#define NBUCK 98              // ceil(50000/512) buckets of 512 nodes
#define EPB 4096              // edges per binning block
#define NB_A ((N_EDGES + EPB - 1) / EPB)   // 391
#define DEGBINS 512

typedef short bf16x8 __attribute__((ext_vector_type(8)));
typedef float f32x4  __attribute__((ext_vector_type(4)));
typedef float f32x2  __attribute__((ext_vector_type(2)));

__device__ __forceinline__ float bf16_raw_to_f32(unsigned short u) {
    return __uint_as_float(((unsigned)u) << 16);
}
__device__ __forceinline__ unsigned short f32_to_bf16_raw(float v) {
    unsigned u = __float_as_uint(v);
    return (unsigned short)((u + 0x7fffu + ((u >> 16) & 1u)) >> 16);
}
__device__ __forceinline__ float load_elem(const void* p, size_t i, int f) {
    if (f) return ((const float*)p)[i];
    return bf16_raw_to_f32(((const unsigned short*)p)[i]);
}
// unpack 8 bf16 into 4 float2 pairs (pair k = dims {2k, 2k+1})
__device__ __forceinline__ void unpack8v(uint4 u, f32x2* f) {
    f[0] = (f32x2){__uint_as_float(u.x << 16), __uint_as_float(u.x & 0xffff0000u)};
    f[1] = (f32x2){__uint_as_float(u.y << 16), __uint_as_float(u.y & 0xffff0000u)};
    f[2] = (f32x2){__uint_as_float(u.z << 16), __uint_as_float(u.z & 0xffff0000u)};
    f[3] = (f32x2){__uint_as_float(u.w << 16), __uint_as_float(u.w & 0xffff0000u)};
}

// ---- dtype probe (verified R4): flag=1 -> fp32 storage. Zeroes bcnt + ghist.
__global__ void detect_dtype_kernel(const unsigned short* __restrict__ w1raw,
                                    int* __restrict__ flag, int* __restrict__ bcnt,
                                    int* __restrict__ ghist) {
    __shared__ float red[256];
    if (threadIdx.x < NBUCK) bcnt[threadIdx.x] = 0;
    ghist[threadIdx.x] = 0;
    ghist[threadIdx.x + 256] = 0;
    float mx = 0.f;
    for (int i = threadIdx.x * 2; i < 16384; i += 512) {
        float v = fabsf(bf16_raw_to_f32(w1raw[i]));
        if (!isnan(v)) mx = fmaxf(mx, v);
    }
    red[threadIdx.x] = mx;
    __syncthreads();
    for (int s = 128; s > 0; s >>= 1) {
        if (threadIdx.x < s) red[threadIdx.x] = fmaxf(red[threadIdx.x], red[threadIdx.x + s]);
        __syncthreads();
    }
    if (threadIdx.x == 0) flag[0] = (red[0] > 1e4f) ? 1 : 0;
}

// ---- prep: W1T[n][k] (128x136 bf16), W2T[n][k] (64x136 bf16) ----
#define WPAD 136
__global__ void prep_kernel(const void* __restrict__ W1, const void* __restrict__ W2,
                            unsigned short* __restrict__ W1T,
                            unsigned short* __restrict__ W2T,
                            const int* __restrict__ flag) {
    const int f = *flag;
    int bid = blockIdx.x, tid = threadIdx.x;
    if (bid < 8) {
        int n = bid * 16 + (tid & 15);
        int kb = (tid >> 4) * 8;
        for (int j = 0; j < 8; ++j)
            W1T[n * WPAD + kb + j] = f32_to_bf16_raw(load_elem(W1, (size_t)(kb + j) * 128 + n, f));
    } else {
        int n = (bid - 8) * 16 + (tid & 15);
        int kb = (tid >> 4) * 8;
        for (int j = 0; j < 8; ++j)
            W2T[n * WPAD + kb + j] = f32_to_bf16_raw(load_elem(W2, (size_t)(kb + j) * 64 + n, f));
    }
}

// ============ binned CSR build (R12-proven) ============
__global__ void bucket_count_kernel(const int* __restrict__ dst,
                                    int* __restrict__ bcnt, int E) {
    __shared__ int hist[NBUCK];
    int t = threadIdx.x;
    if (t < NBUCK) hist[t] = 0;
    __syncthreads();
    int e0 = blockIdx.x * EPB;
    for (int k = 0; k < 16; ++k) {
        int e = e0 + k * 256 + t;
        if (e < E) atomicAdd(&hist[dst[e] >> 9], 1);
    }
    __syncthreads();
    if (t < NBUCK && hist[t]) atomicAdd(&bcnt[t], hist[t]);
}

__global__ void bucket_scan_kernel(const int* __restrict__ bcnt,
                                   int* __restrict__ bbase, int* __restrict__ bcur) {
    __shared__ int tmp[128];
    int t = threadIdx.x;
    int v = (t < NBUCK) ? bcnt[t] : 0;
    tmp[t] = v;
    __syncthreads();
    for (int off = 1; off < 128; off <<= 1) {
        int x = (t >= off) ? tmp[t - off] : 0;
        __syncthreads();
        tmp[t] += x;
        __syncthreads();
    }
    if (t < NBUCK) { int ex = tmp[t] - v; bbase[t] = ex; bcur[t] = ex; }
    if (t == NBUCK - 1) bbase[NBUCK] = tmp[t];
}

__global__ void binA_kernel(const int* __restrict__ src, const int* __restrict__ dst,
                            int* __restrict__ bcur, unsigned* __restrict__ inter, int E) {
    __shared__ int hist[NBUCK], gbase[NBUCK], cur[NBUCK];
    int t = threadIdx.x;
    if (t < NBUCK) hist[t] = 0;
    __syncthreads();
    int e0 = blockIdx.x * EPB;
    for (int k = 0; k < 16; ++k) {
        int e = e0 + k * 256 + t;
        if (e < E) atomicAdd(&hist[dst[e] >> 9], 1);
    }
    __syncthreads();
    if (t < NBUCK) {
        int hv = hist[t];
        gbase[t] = hv ? atomicAdd(&bcur[t], hv) : 0;
        cur[t] = 0;
    }
    __syncthreads();
    for (int k = 0; k < 16; ++k) {
        int e = e0 + k * 256 + t;
        if (e < E) {
            int d = dst[e];
            int b = d >> 9;
            int off = atomicAdd(&cur[b], 1);
            inter[gbase[b] + off] = (unsigned)src[e] | ((unsigned)(d & 511) << 16);
        }
    }
}

// binB also feeds the global degree histogram (for the balance worklist).
__global__ void binB_kernel(const unsigned* __restrict__ inter,
                            const int* __restrict__ bbase,
                            int* __restrict__ csr_src, int* __restrict__ start,
                            int* __restrict__ ghist,
                            int N, int E) {
    int b = blockIdx.x;
    int node0 = b << 9;
    int lo = bbase[b], hi = bbase[b + 1];
    __shared__ int hist[512];
    __shared__ int t2[256];
    int t = threadIdx.x;
    hist[t] = 0; hist[t + 256] = 0;
    __syncthreads();
    for (int e = lo + t; e < hi; e += 256) atomicAdd(&hist[inter[e] >> 16], 1);
    __syncthreads();
    int s0 = hist[2 * t], s1 = hist[2 * t + 1];
    int nodeCnt = min(512, N - node0);
    if (2 * t < nodeCnt)     atomicAdd(&ghist[min(s0, DEGBINS - 1)], 1);
    if (2 * t + 1 < nodeCnt) atomicAdd(&ghist[min(s1, DEGBINS - 1)], 1);
    t2[t] = s0 + s1;
    __syncthreads();
    for (int off = 1; off < 256; off <<= 1) {
        int x = (t >= off) ? t2[t - off] : 0;
        __syncthreads();
        t2[t] += x;
        __syncthreads();
    }
    int base = (t == 0) ? 0 : t2[t - 1];
    hist[2 * t] = base;
    hist[2 * t + 1] = base + s0;
    __syncthreads();
    for (int i = t; i < nodeCnt; i += 256) start[node0 + i] = lo + hist[i];
    if (b == NBUCK - 1 && t == 0) start[N] = E;
    __syncthreads();
    for (int e = lo + t; e < hi; e += 256) {
        unsigned u = inter[e];
        int slot = lo + atomicAdd(&hist[u >> 16], 1);
        csr_src[slot] = (int)(u & 0xffffu);
    }
}

// ---- degree-sorted worklist: scan 512 bins, scatter nodes descending ----
__global__ void degscan_kernel(const int* __restrict__ ghist, int* __restrict__ gcur) {
    __shared__ int tmp[DEGBINS];
    int t = threadIdx.x;
    int v = ghist[t];
    tmp[t] = v;
    __syncthreads();
    for (int off = 1; off < DEGBINS; off <<= 1) {
        int x = (t >= off) ? tmp[t - off] : 0;
        __syncthreads();
        tmp[t] += x;
        __syncthreads();
    }
    gcur[t] = tmp[t] - v;   // exclusive base (ascending)
}

__global__ void degscatter_kernel(const int* __restrict__ start,
                                  int* __restrict__ gcur,
                                  int* __restrict__ wl, int N) {
    int i = blockIdx.x * 256 + threadIdx.x;
    if (i >= N) return;
    int deg = start[i + 1] - start[i];
    int off = atomicAdd(&gcur[min(deg, DEGBINS - 1)], 1);
    wl[N - 1 - off] = i;    // descending degree: heavy waves launch first
}

// ---- MFMA GEMM1 (R9-proven) ----
__global__ void gemm1_mfma_kernel(const void* __restrict__ h,
                                  const unsigned short* __restrict__ W1T,
                                  unsigned short* __restrict__ feat1, int N,
                                  const int* __restrict__ flag) {
    const int f = *flag;
    int lane = threadIdx.x & 63;
    int rbase = blockIdx.x * 64 + (threadIdx.x >> 6) * 16;
    int arow = rbase + (lane & 15);
    int arowc = min(arow, N - 1);
    int kb0 = (lane >> 4) * 8;

    f32x4 acc[8];
#pragma unroll
    for (int t = 0; t < 8; ++t) acc[t] = (f32x4){0.f, 0.f, 0.f, 0.f};

#pragma unroll
    for (int ks = 0; ks < 4; ++ks) {
        int kb = ks * 32 + kb0;
        bf16x8 afrag;
        if (f == 0) {
            afrag = *(const bf16x8*)((const unsigned short*)h + (size_t)arowc * 128 + kb);
        } else {
            const float* hp = (const float*)h + (size_t)arowc * 128 + kb;
#pragma unroll
            for (int j = 0; j < 8; ++j) afrag[j] = (short)f32_to_bf16_raw(hp[j]);
        }
#pragma unroll
        for (int t = 0; t < 8; ++t) {
            int n = t * 16 + (lane & 15);
            bf16x8 bfrag = *(const bf16x8*)(W1T + n * WPAD + kb);
            acc[t] = __builtin_amdgcn_mfma_f32_16x16x32_bf16(afrag, bfrag, acc[t], 0, 0, 0);
        }
    }
    int orow0 = rbase + (lane >> 4) * 4;
    int col = lane & 15;
#pragma unroll
    for (int t = 0; t < 8; ++t)
#pragma unroll
        for (int r = 0; r < 4; ++r) {
            int row = orow0 + r;
            if (row < N)
                feat1[(size_t)row * 128 + t * 16 + col] = f32_to_bf16_raw(acc[t][r]);
        }
}

// ---- MFMA GEMM2 (R9-proven) ----
__global__ void gemm2_mfma_kernel(const unsigned short* __restrict__ agg1e,
                                  const unsigned short* __restrict__ W2T,
                                  unsigned short* __restrict__ feat2, int N) {
    int lane = threadIdx.x & 63;
    int rbase = blockIdx.x * 64 + (threadIdx.x >> 6) * 16;
    int arow = rbase + (lane & 15);
    int arowc = min(arow, N - 1);
    int kb0 = (lane >> 4) * 8;

    f32x4 acc[4];
#pragma unroll
    for (int t = 0; t < 4; ++t) acc[t] = (f32x4){0.f, 0.f, 0.f, 0.f};

#pragma unroll
    for (int ks = 0; ks < 4; ++ks) {
        int kb = ks * 32 + kb0;
        bf16x8 afrag = *(const bf16x8*)(agg1e + (size_t)arowc * 128 + kb);
#pragma unroll
        for (int t = 0; t < 4; ++t) {
            int n = t * 16 + (lane & 15);
            bf16x8 bfrag = *(const bf16x8*)(W2T + n * WPAD + kb);
            acc[t] = __builtin_amdgcn_mfma_f32_16x16x32_bf16(afrag, bfrag, acc[t], 0, 0, 0);
        }
    }
    int orow0 = rbase + (lane >> 4) * 4;
    int col = lane & 15;
#pragma unroll
    for (int t = 0; t < 4; ++t)
#pragma unroll
        for (int r = 0; r < 4; ++r) {
            int row = orow0 + r;
            if (row < N)
                feat2[(size_t)row * 64 + t * 16 + col] = f32_to_bf16_raw(acc[t][r]);
        }
}

// ======= layer 1 fused GAT (R15) =======
// Wave = 8 dsts (one per 8-lane group, degree-matched via worklist).
// Lane owns one full head (16 dims = 2 uint4): the 16-dim head dot is
// lane-local -> ZERO shfl per edge, ZERO cross-group merge per node.
// 2-edge unroll = 4 outstanding 16B gathers/lane.
__global__ void gat1_kernel(const unsigned short* __restrict__ feat1,
                            const int* __restrict__ csr_src,
                            const int* __restrict__ start,
                            const int* __restrict__ wl,
                            unsigned short* __restrict__ agg1e, int N) {
    int wave = blockIdx.x * 4 + (threadIdx.x >> 6);
    int lane = threadIdx.x & 63;
    int g = lane >> 3, gl = lane & 7;          // group=dst, gl=head
    int nidx = wave * 8 + g;
    if (nidx >= N) return;
    int dstn = wl[nidx];

    const char* fb = (const char*)feat1;       // row = 256 B
    unsigned loff = (unsigned)gl << 5;         // 32 B per head
    unsigned drow = ((unsigned)dstn << 8) + loff;
    f32x2 fd2[8];
    unpack8v(*(const uint4*)(fb + drow), fd2);
    unpack8v(*(const uint4*)(fb + drow + 16), fd2 + 4);

    float l = 0.f;
    f32x2 acc2[8];
#pragma unroll
    for (int k = 0; k < 8; ++k) acc2[k] = (f32x2){0.f, 0.f};

    int e0 = start[dstn], e1 = start[dstn + 1];
    int base = e0;
    for (; base + 2 <= e1; base += 2) {
        int s0 = csr_src[base], s1 = csr_src[base + 1];
        const char* r0 = fb + ((unsigned)s0 << 8) + loff;
        const char* r1 = fb + ((unsigned)s1 << 8) + loff;
        uint4 a0 = *(const uint4*)r0, a1 = *(const uint4*)(r0 + 16);
        uint4 b0 = *(const uint4*)r1, b1 = *(const uint4*)(r1 + 16);
        f32x2 f0[8], f1[8];
        unpack8v(a0, f0); unpack8v(a1, f0 + 4);
        unpack8v(b0, f1); unpack8v(b1, f1 + 4);
        f32x2 p0 = fd2[0] * f0[0];
        f32x2 p1 = fd2[0] * f1[0];
#pragma unroll
        for (int k = 1; k < 8; ++k) { p0 += fd2[k] * f0[k]; p1 += fd2[k] * f1[k]; }
        float q0 = p0.x + p0.y;
        float q1 = p1.x + p1.y;
        float w0 = __expf(q0 * 0.25f);
        float w1 = __expf(q1 * 0.25f);
        f32x2 W0 = (f32x2){w0, w0}, W1 = (f32x2){w1, w1};
#pragma unroll
        for (int k = 0; k < 8; ++k) {
            acc2[k] += W0 * f0[k];
            acc2[k] += W1 * f1[k];
        }
        l += w0 + w1;
    }
    if (base < e1) {
        int s = csr_src[base];
        const char* r0 = fb + ((unsigned)s << 8) + loff;
        uint4 a0 = *(const uint4*)r0, a1 = *(const uint4*)(r0 + 16);
        f32x2 fv[8];
        unpack8v(a0, fv); unpack8v(a1, fv + 4);
        f32x2 p = fd2[0] * fv[0];
#pragma unroll
        for (int k = 1; k < 8; ++k) p += fd2[k] * fv[k];
        float w = __expf((p.x + p.y) * 0.25f);
        f32x2 W = (f32x2){w, w};
#pragma unroll
        for (int k = 0; k < 8; ++k) acc2[k] += W * fv[k];
        l += w;
    }
    float rcp = 1.f / fmaxf(l, 1e-9f);
    unsigned pk[8];
#pragma unroll
    for (int k = 0; k < 8; ++k) {
        float x0 = acc2[k].x * rcp, x1 = acc2[k].y * rcp;
        x0 = (x0 > 0.f) ? x0 : expm1f(x0);     // ELU fused
        x1 = (x1 > 0.f) ? x1 : expm1f(x1);
        pk[k] = (unsigned)f32_to_bf16_raw(x0) | ((unsigned)f32_to_bf16_raw(x1) << 16);
    }
    *(uint4*)((char*)agg1e + drow)      = (uint4){pk[0], pk[1], pk[2], pk[3]};
    *(uint4*)((char*)agg1e + drow + 16) = (uint4){pk[4], pk[5], pk[6], pk[7]};
}

// ======= layer 2 fused GAT (R15) =======
// Wave = 8 dsts (8-lane groups via worklist); lane = 8 dims (1 uint4).
// 64-dim dot needs 3 intra-group shfls/edge; no per-node merge.
__global__ void gat2_kernel(const unsigned short* __restrict__ feat2,
                            const int* __restrict__ csr_src,
                            const int* __restrict__ start,
                            const int* __restrict__ wl,
                            void* __restrict__ out, int N,
                            const int* __restrict__ flag) {
    int wave = blockIdx.x * 4 + (threadIdx.x >> 6);
    int lane = threadIdx.x & 63;
    int g = lane >> 3, gl = lane & 7;
    int nidx = wave * 8 + g;
    if (nidx >= N) return;
    int dstn = wl[nidx];
    const int f = *flag;

    const char* fb = (const char*)feat2;       // row = 128 B
    unsigned loff = (unsigned)gl << 4;         // 16 B per lane
    unsigned drow = ((unsigned)dstn << 7) + loff;
    f32x2 fd2[4];
    unpack8v(*(const uint4*)(fb + drow), fd2);

    float l = 0.f;
    f32x2 acc2[4];
#pragma unroll
    for (int k = 0; k < 4; ++k) acc2[k] = (f32x2){0.f, 0.f};

    int e0 = start[dstn], e1 = start[dstn + 1];
    int base = e0;
    for (; base + 2 <= e1; base += 2) {
        int s0 = csr_src[base], s1 = csr_src[base + 1];
        uint4 u0 = *(const uint4*)(fb + ((unsigned)s0 << 7) + loff);
        uint4 u1 = *(const uint4*)(fb + ((unsigned)s1 << 7) + loff);
        f32x2 f0[4], f1[4];
        unpack8v(u0, f0); unpack8v(u1, f1);
        f32x2 p0 = fd2[0] * f0[0];
        f32x2 p1 = fd2[0] * f1[0];
#pragma unroll
        for (int k = 1; k < 4; ++k) { p0 += fd2[k] * f0[k]; p1 += fd2[k] * f1[k]; }
        float q0 = p0.x + p0.y;
        float q1 = p1.x + p1.y;
        q0 += __shfl_xor(q0, 1); q1 += __shfl_xor(q1, 1);
        q0 += __shfl_xor(q0, 2); q1 += __shfl_xor(q1, 2);
        q0 += __shfl_xor(q0, 4); q1 += __shfl_xor(q1, 4);
        float w0 = __expf(q0 * 0.125f);
        float w1 = __expf(q1 * 0.125f);
        f32x2 W0 = (f32x2){w0, w0}, W1 = (f32x2){w1, w1};
#pragma unroll
        for (int k = 0; k < 4; ++k) {
            acc2[k] += W0 * f0[k];
            acc2[k] += W1 * f1[k];
        }
        l += w0 + w1;
    }
    if (base < e1) {
        int s = csr_src[base];
        uint4 u = *(const uint4*)(fb + ((unsigned)s << 7) + loff);
        f32x2 fv[4];
        unpack8v(u, fv);
        f32x2 p = fd2[0] * fv[0];
#pragma unroll
        for (int k = 1; k < 4; ++k) p += fd2[k] * fv[k];
        float q = p.x + p.y;
        q += __shfl_xor(q, 1);
        q += __shfl_xor(q, 2);
        q += __shfl_xor(q, 4);
        float w = __expf(q * 0.125f);
        f32x2 W = (f32x2){w, w};
#pragma unroll
        for (int k = 0; k < 4; ++k) acc2[k] += W * fv[k];
        l += w;
    }
    float rcp = 1.f / fmaxf(l, 1e-9f);
    float v[8];
#pragma unroll
    for (int k = 0; k < 4; ++k) {
        v[2 * k]     = acc2[k].x * rcp;
        v[2 * k + 1] = acc2[k].y * rcp;
    }
    if (f) {
        float* op = (float*)out + ((size_t)dstn << 6) + (gl << 3);
        *(float4*)(op)     = (float4){v[0], v[1], v[2], v[3]};
        *(float4*)(op + 4) = (float4){v[4], v[5], v[6], v[7]};
    } else {
        uint4 pk;
        pk.x = (unsigned)f32_to_bf16_raw(v[0]) | ((unsigned)f32_to_bf16_raw(v[1]) << 16);
        pk.y = (unsigned)f32_to_bf16_raw(v[2]) | ((unsigned)f32_to_bf16_raw(v[3]) << 16);
        pk.z = (unsigned)f32_to_bf16_raw(v[4]) | ((unsigned)f32_to_bf16_raw(v[5]) << 16);
        pk.w = (unsigned)f32_to_bf16_raw(v[6]) | ((unsigned)f32_to_bf16_raw(v[7]) << 16);
        *(uint4*)((unsigned short*)out + ((size_t)dstn << 6) + (gl << 3)) = pk;
    }
}

extern "C" void kernel_launch(void* const* d_in, const int* in_sizes, int n_in,
                              void* d_out, int out_size, void* d_ws, size_t ws_size,
                              hipStream_t stream) {
    const void* h  = d_in[0];
    const void* W1 = d_in[1];
    const void* W2 = d_in[2];
    const int* src = (const int*)d_in[3];
    const int* dst = (const int*)d_in[4];

    float* ws = (float*)d_ws;
    // Layout (4-byte words), peak ~45.5 MB (unchanged footprint).
    unsigned short* feat1 = (unsigned short*)ws;
    unsigned short* agg1e = (unsigned short*)(ws + 3200000);
    unsigned short* feat2 = (unsigned short*)ws;      // after feat1 dead
    unsigned* inter       = (unsigned*)(ws + 6400000);
    int*   wl             = (int*)(ws + 6400000);     // overlays inter (dead after binB)
    int*   csr_src        = (int*)(ws + 9600000);
    int*   start          = (int*)(ws + 11200000);
    int*   flag           = (int*)(ws + 11330000);
    int*   bcnt           = (int*)(ws + 11331000);
    int*   bbase          = (int*)(ws + 11332000);
    int*   bcur           = (int*)(ws + 11333000);
    int*   ghist          = (int*)(ws + 11334000);    // 512 ints
    int*   gcur           = (int*)(ws + 11335000);    // 512 ints
    unsigned short* W1T   = (unsigned short*)(ws + 11340000);
    unsigned short* W2T   = (unsigned short*)(ws + 11350000);

    detect_dtype_kernel<<<1, 256, 0, stream>>>((const unsigned short*)W1, flag, bcnt, ghist);
    prep_kernel<<<12, 256, 0, stream>>>(W1, W2, W1T, W2T, flag);

    // ---- binned CSR build (by dst), storing src ids ----
    bucket_count_kernel<<<NB_A, 256, 0, stream>>>(dst, bcnt, N_EDGES);
    bucket_scan_kernel<<<1, 128, 0, stream>>>(bcnt, bbase, bcur);
    binA_kernel<<<NB_A, 256, 0, stream>>>(src, dst, bcur, inter, N_EDGES);
    binB_kernel<<<NBUCK, 256, 0, stream>>>(inter, bbase, csr_src, start, ghist, N_NODES, N_EDGES);

    // ---- degree-sorted worklist (balances 8 dsts/wave in gat kernels) ----
    degscan_kernel<<<1, DEGBINS, 0, stream>>>(ghist, gcur);
    degscatter_kernel<<<(N_NODES + 255) / 256, 256, 0, stream>>>(start, gcur, wl, N_NODES);

    gemm1_mfma_kernel<<<(N_NODES + 63) / 64, 256, 0, stream>>>(h, W1T, feat1, N_NODES, flag);
    // 8 dsts per wave -> ceil(N/8) waves, 4 waves per block
    int nwaves = (N_NODES + 7) / 8;
    gat1_kernel<<<(nwaves + 3) / 4, 256, 0, stream>>>(feat1, csr_src, start, wl, agg1e, N_NODES);
    gemm2_mfma_kernel<<<(N_NODES + 63) / 64, 256, 0, stream>>>(agg1e, W2T, feat2, N_NODES);
    gat2_kernel<<<(nwaves + 3) / 4, 256, 0, stream>>>(feat2, csr_src, start, wl, d_out, N_NODES, flag);
}

// Round 3
// 293.509 us; speedup vs baseline: 1.7725x; 1.7725x over previous
//
#include <hip/hip_runtime.h>
#include <hip/hip_bf16.h>

#define N_NODES 50000
#define N_EDGES 1600000
#define NBUCK 98              // ceil(50000/512) buckets of 512 nodes
#define EPB 4096              // edges per binning block
#define NB_A ((N_EDGES + EPB - 1) / EPB)   // 391

typedef short bf16x8 __attribute__((ext_vector_type(8)));
typedef float f32x4  __attribute__((ext_vector_type(4)));
typedef float f32x2  __attribute__((ext_vector_type(2)));

__device__ __forceinline__ float bf16_raw_to_f32(unsigned short u) {
    return __uint_as_float(((unsigned)u) << 16);
}
__device__ __forceinline__ unsigned short f32_to_bf16_raw(float v) {
    unsigned u = __float_as_uint(v);
    return (unsigned short)((u + 0x7fffu + ((u >> 16) & 1u)) >> 16);
}
__device__ __forceinline__ float load_elem(const void* p, size_t i, int f) {
    if (f) return ((const float*)p)[i];
    return bf16_raw_to_f32(((const unsigned short*)p)[i]);
}
// unpack 8 bf16 into 4 float2 pairs (pair k = dims {2k, 2k+1})
__device__ __forceinline__ void unpack8v(uint4 u, f32x2* f) {
    f[0] = (f32x2){__uint_as_float(u.x << 16), __uint_as_float(u.x & 0xffff0000u)};
    f[1] = (f32x2){__uint_as_float(u.y << 16), __uint_as_float(u.y & 0xffff0000u)};
    f[2] = (f32x2){__uint_as_float(u.z << 16), __uint_as_float(u.z & 0xffff0000u)};
    f[3] = (f32x2){__uint_as_float(u.w << 16), __uint_as_float(u.w & 0xffff0000u)};
}

// ---- dtype probe (verified R4): flag=1 -> fp32 storage. Also zeroes bcnt.
__global__ void detect_dtype_kernel(const unsigned short* __restrict__ w1raw,
                                    int* __restrict__ flag, int* __restrict__ bcnt) {
    __shared__ float red[256];
    if (threadIdx.x < NBUCK) bcnt[threadIdx.x] = 0;
    float mx = 0.f;
    for (int i = threadIdx.x * 2; i < 16384; i += 512) {
        float v = fabsf(bf16_raw_to_f32(w1raw[i]));
        if (!isnan(v)) mx = fmaxf(mx, v);
    }
    red[threadIdx.x] = mx;
    __syncthreads();
    for (int s = 128; s > 0; s >>= 1) {
        if (threadIdx.x < s) red[threadIdx.x] = fmaxf(red[threadIdx.x], red[threadIdx.x + s]);
        __syncthreads();
    }
    if (threadIdx.x == 0) flag[0] = (red[0] > 1e4f) ? 1 : 0;
}

// ---- prep: W1T[n][k] (128x136 bf16), W2T[n][k] (64x136 bf16) ----
#define WPAD 136
__global__ void prep_kernel(const void* __restrict__ W1, const void* __restrict__ W2,
                            unsigned short* __restrict__ W1T,
                            unsigned short* __restrict__ W2T,
                            const int* __restrict__ flag) {
    const int f = *flag;
    int bid = blockIdx.x, tid = threadIdx.x;
    if (bid < 8) {
        int n = bid * 16 + (tid & 15);
        int kb = (tid >> 4) * 8;
        for (int j = 0; j < 8; ++j)
            W1T[n * WPAD + kb + j] = f32_to_bf16_raw(load_elem(W1, (size_t)(kb + j) * 128 + n, f));
    } else {
        int n = (bid - 8) * 16 + (tid & 15);
        int kb = (tid >> 4) * 8;
        for (int j = 0; j < 8; ++j)
            W2T[n * WPAD + kb + j] = f32_to_bf16_raw(load_elem(W2, (size_t)(kb + j) * 64 + n, f));
    }
}

// ============ binned CSR build (R12-proven, no ghist) ============
__global__ void bucket_count_kernel(const int* __restrict__ dst,
                                    int* __restrict__ bcnt, int E) {
    __shared__ int hist[NBUCK];
    int t = threadIdx.x;
    if (t < NBUCK) hist[t] = 0;
    __syncthreads();
    int e0 = blockIdx.x * EPB;
    for (int k = 0; k < 16; ++k) {
        int e = e0 + k * 256 + t;
        if (e < E) atomicAdd(&hist[dst[e] >> 9], 1);
    }
    __syncthreads();
    if (t < NBUCK && hist[t]) atomicAdd(&bcnt[t], hist[t]);
}

__global__ void bucket_scan_kernel(const int* __restrict__ bcnt,
                                   int* __restrict__ bbase, int* __restrict__ bcur) {
    __shared__ int tmp[128];
    int t = threadIdx.x;
    int v = (t < NBUCK) ? bcnt[t] : 0;
    tmp[t] = v;
    __syncthreads();
    for (int off = 1; off < 128; off <<= 1) {
        int x = (t >= off) ? tmp[t - off] : 0;
        __syncthreads();
        tmp[t] += x;
        __syncthreads();
    }
    if (t < NBUCK) { int ex = tmp[t] - v; bbase[t] = ex; bcur[t] = ex; }
    if (t == NBUCK - 1) bbase[NBUCK] = tmp[t];
}

__global__ void binA_kernel(const int* __restrict__ src, const int* __restrict__ dst,
                            int* __restrict__ bcur, unsigned* __restrict__ inter, int E) {
    __shared__ int hist[NBUCK], gbase[NBUCK], cur[NBUCK];
    int t = threadIdx.x;
    if (t < NBUCK) hist[t] = 0;
    __syncthreads();
    int e0 = blockIdx.x * EPB;
    for (int k = 0; k < 16; ++k) {
        int e = e0 + k * 256 + t;
        if (e < E) atomicAdd(&hist[dst[e] >> 9], 1);
    }
    __syncthreads();
    if (t < NBUCK) {
        int hv = hist[t];
        gbase[t] = hv ? atomicAdd(&bcur[t], hv) : 0;
        cur[t] = 0;
    }
    __syncthreads();
    for (int k = 0; k < 16; ++k) {
        int e = e0 + k * 256 + t;
        if (e < E) {
            int d = dst[e];
            int b = d >> 9;
            int off = atomicAdd(&cur[b], 1);
            inter[gbase[b] + off] = (unsigned)src[e] | ((unsigned)(d & 511) << 16);
        }
    }
}

__global__ void binB_kernel(const unsigned* __restrict__ inter,
                            const int* __restrict__ bbase,
                            int* __restrict__ csr_src, int* __restrict__ start,
                            int N, int E) {
    int b = blockIdx.x;
    int node0 = b << 9;
    int lo = bbase[b], hi = bbase[b + 1];
    __shared__ int hist[512];
    __shared__ int t2[256];
    int t = threadIdx.x;
    hist[t] = 0; hist[t + 256] = 0;
    __syncthreads();
    for (int e = lo + t; e < hi; e += 256) atomicAdd(&hist[inter[e] >> 16], 1);
    __syncthreads();
    int s0 = hist[2 * t], s1 = hist[2 * t + 1];
    t2[t] = s0 + s1;
    __syncthreads();
    for (int off = 1; off < 256; off <<= 1) {
        int x = (t >= off) ? t2[t - off] : 0;
        __syncthreads();
        t2[t] += x;
        __syncthreads();
    }
    int base = (t == 0) ? 0 : t2[t - 1];
    hist[2 * t] = base;
    hist[2 * t + 1] = base + s0;
    __syncthreads();
    int nodeCnt = min(512, N - node0);
    for (int i = t; i < nodeCnt; i += 256) start[node0 + i] = lo + hist[i];
    if (b == NBUCK - 1 && t == 0) start[N] = E;
    __syncthreads();
    for (int e = lo + t; e < hi; e += 256) {
        unsigned u = inter[e];
        int slot = lo + atomicAdd(&hist[u >> 16], 1);
        csr_src[slot] = (int)(u & 0xffffu);
    }
}

// ---- MFMA GEMM1 (R9-proven) ----
__global__ void gemm1_mfma_kernel(const void* __restrict__ h,
                                  const unsigned short* __restrict__ W1T,
                                  unsigned short* __restrict__ feat1, int N,
                                  const int* __restrict__ flag) {
    const int f = *flag;
    int lane = threadIdx.x & 63;
    int rbase = blockIdx.x * 64 + (threadIdx.x >> 6) * 16;
    int arow = rbase + (lane & 15);
    int arowc = min(arow, N - 1);
    int kb0 = (lane >> 4) * 8;

    f32x4 acc[8];
#pragma unroll
    for (int t = 0; t < 8; ++t) acc[t] = (f32x4){0.f, 0.f, 0.f, 0.f};

#pragma unroll
    for (int ks = 0; ks < 4; ++ks) {
        int kb = ks * 32 + kb0;
        bf16x8 afrag;
        if (f == 0) {
            afrag = *(const bf16x8*)((const unsigned short*)h + (size_t)arowc * 128 + kb);
        } else {
            const float* hp = (const float*)h + (size_t)arowc * 128 + kb;
#pragma unroll
            for (int j = 0; j < 8; ++j) afrag[j] = (short)f32_to_bf16_raw(hp[j]);
        }
#pragma unroll
        for (int t = 0; t < 8; ++t) {
            int n = t * 16 + (lane & 15);
            bf16x8 bfrag = *(const bf16x8*)(W1T + n * WPAD + kb);
            acc[t] = __builtin_amdgcn_mfma_f32_16x16x32_bf16(afrag, bfrag, acc[t], 0, 0, 0);
        }
    }
    int orow0 = rbase + (lane >> 4) * 4;
    int col = lane & 15;
#pragma unroll
    for (int t = 0; t < 8; ++t)
#pragma unroll
        for (int r = 0; r < 4; ++r) {
            int row = orow0 + r;
            if (row < N)
                feat1[(size_t)row * 128 + t * 16 + col] = f32_to_bf16_raw(acc[t][r]);
        }
}

// ---- MFMA GEMM2 (R9-proven) ----
__global__ void gemm2_mfma_kernel(const unsigned short* __restrict__ agg1e,
                                  const unsigned short* __restrict__ W2T,
                                  unsigned short* __restrict__ feat2, int N) {
    int lane = threadIdx.x & 63;
    int rbase = blockIdx.x * 64 + (threadIdx.x >> 6) * 16;
    int arow = rbase + (lane & 15);
    int arowc = min(arow, N - 1);
    int kb0 = (lane >> 4) * 8;

    f32x4 acc[4];
#pragma unroll
    for (int t = 0; t < 4; ++t) acc[t] = (f32x4){0.f, 0.f, 0.f, 0.f};

#pragma unroll
    for (int ks = 0; ks < 4; ++ks) {
        int kb = ks * 32 + kb0;
        bf16x8 afrag = *(const bf16x8*)(agg1e + (size_t)arowc * 128 + kb);
#pragma unroll
        for (int t = 0; t < 4; ++t) {
            int n = t * 16 + (lane & 15);
            bf16x8 bfrag = *(const bf16x8*)(W2T + n * WPAD + kb);
            acc[t] = __builtin_amdgcn_mfma_f32_16x16x32_bf16(afrag, bfrag, acc[t], 0, 0, 0);
        }
    }
    int orow0 = rbase + (lane >> 4) * 4;
    int col = lane & 15;
#pragma unroll
    for (int t = 0; t < 4; ++t)
#pragma unroll
        for (int r = 0; r < 4; ++r) {
            int row = orow0 + r;
            if (row < N)
                feat2[(size_t)row * 64 + t * 16 + col] = f32_to_bf16_raw(acc[t][r]);
        }
}

// ======= layer 1 fused GAT (R16) =======
// Wave = 8 CONSECUTIVE dsts (one per 8-lane group, natural order: no
// worklist; skew = E[max of 8 Poisson(32)] ~ +25%, paid instead of the
// R15 worklist kernels whose contended atomics cost ~230 us).
// Lane owns one full head (16 dims = 2 uint4): head dot is lane-local ->
// ZERO shfl per edge, ZERO cross-group merge per node. Natural order also
// gives adjacent csr ranges per wave + fully coalesced output writes.
__global__ void gat1_kernel(const unsigned short* __restrict__ feat1,
                            const int* __restrict__ csr_src,
                            const int* __restrict__ start,
                            unsigned short* __restrict__ agg1e, int N) {
    int wave = blockIdx.x * 4 + (threadIdx.x >> 6);
    int lane = threadIdx.x & 63;
    int g = lane >> 3, gl = lane & 7;          // group=dst, gl=head
    int dstn = wave * 8 + g;
    if (dstn >= N) return;

    const char* fb = (const char*)feat1;       // row = 256 B
    unsigned loff = (unsigned)gl << 5;         // 32 B per head
    unsigned drow = ((unsigned)dstn << 8) + loff;
    f32x2 fd2[8];
    unpack8v(*(const uint4*)(fb + drow), fd2);
    unpack8v(*(const uint4*)(fb + drow + 16), fd2 + 4);

    float l = 0.f;
    f32x2 acc2[8];
#pragma unroll
    for (int k = 0; k < 8; ++k) acc2[k] = (f32x2){0.f, 0.f};

    int e0 = start[dstn], e1 = start[dstn + 1];
    int base = e0;
    for (; base + 2 <= e1; base += 2) {
        int s0 = csr_src[base], s1 = csr_src[base + 1];
        const char* r0 = fb + ((unsigned)s0 << 8) + loff;
        const char* r1 = fb + ((unsigned)s1 << 8) + loff;
        uint4 a0 = *(const uint4*)r0, a1 = *(const uint4*)(r0 + 16);
        uint4 b0 = *(const uint4*)r1, b1 = *(const uint4*)(r1 + 16);
        f32x2 f0[8], f1[8];
        unpack8v(a0, f0); unpack8v(a1, f0 + 4);
        unpack8v(b0, f1); unpack8v(b1, f1 + 4);
        f32x2 p0 = fd2[0] * f0[0];
        f32x2 p1 = fd2[0] * f1[0];
#pragma unroll
        for (int k = 1; k < 8; ++k) { p0 += fd2[k] * f0[k]; p1 += fd2[k] * f1[k]; }
        float q0 = p0.x + p0.y;
        float q1 = p1.x + p1.y;
        float w0 = __expf(q0 * 0.25f);
        float w1 = __expf(q1 * 0.25f);
        f32x2 W0 = (f32x2){w0, w0}, W1 = (f32x2){w1, w1};
#pragma unroll
        for (int k = 0; k < 8; ++k) {
            acc2[k] += W0 * f0[k];
            acc2[k] += W1 * f1[k];
        }
        l += w0 + w1;
    }
    if (base < e1) {
        int s = csr_src[base];
        const char* r0 = fb + ((unsigned)s << 8) + loff;
        uint4 a0 = *(const uint4*)r0, a1 = *(const uint4*)(r0 + 16);
        f32x2 fv[8];
        unpack8v(a0, fv); unpack8v(a1, fv + 4);
        f32x2 p = fd2[0] * fv[0];
#pragma unroll
        for (int k = 1; k < 8; ++k) p += fd2[k] * fv[k];
        float w = __expf((p.x + p.y) * 0.25f);
        f32x2 W = (f32x2){w, w};
#pragma unroll
        for (int k = 0; k < 8; ++k) acc2[k] += W * fv[k];
        l += w;
    }
    float rcp = 1.f / fmaxf(l, 1e-9f);
    unsigned pk[8];
#pragma unroll
    for (int k = 0; k < 8; ++k) {
        float x0 = acc2[k].x * rcp, x1 = acc2[k].y * rcp;
        x0 = (x0 > 0.f) ? x0 : expm1f(x0);     // ELU fused
        x1 = (x1 > 0.f) ? x1 : expm1f(x1);
        pk[k] = (unsigned)f32_to_bf16_raw(x0) | ((unsigned)f32_to_bf16_raw(x1) << 16);
    }
    *(uint4*)((char*)agg1e + drow)      = (uint4){pk[0], pk[1], pk[2], pk[3]};
    *(uint4*)((char*)agg1e + drow + 16) = (uint4){pk[4], pk[5], pk[6], pk[7]};
}

// ======= layer 2 fused GAT (R16) =======
// Wave = 8 consecutive dsts (8-lane groups); lane = 8 dims (1 uint4).
// 64-dim dot needs 3 intra-group shfls/edge; no per-node merge.
__global__ void gat2_kernel(const unsigned short* __restrict__ feat2,
                            const int* __restrict__ csr_src,
                            const int* __restrict__ start,
                            void* __restrict__ out, int N,
                            const int* __restrict__ flag) {
    int wave = blockIdx.x * 4 + (threadIdx.x >> 6);
    int lane = threadIdx.x & 63;
    int g = lane >> 3, gl = lane & 7;
    int dstn = wave * 8 + g;
    if (dstn >= N) return;
    const int f = *flag;

    const char* fb = (const char*)feat2;       // row = 128 B
    unsigned loff = (unsigned)gl << 4;         // 16 B per lane
    unsigned drow = ((unsigned)dstn << 7) + loff;
    f32x2 fd2[4];
    unpack8v(*(const uint4*)(fb + drow), fd2);

    float l = 0.f;
    f32x2 acc2[4];
#pragma unroll
    for (int k = 0; k < 4; ++k) acc2[k] = (f32x2){0.f, 0.f};

    int e0 = start[dstn], e1 = start[dstn + 1];
    int base = e0;
    for (; base + 2 <= e1; base += 2) {
        int s0 = csr_src[base], s1 = csr_src[base + 1];
        uint4 u0 = *(const uint4*)(fb + ((unsigned)s0 << 7) + loff);
        uint4 u1 = *(const uint4*)(fb + ((unsigned)s1 << 7) + loff);
        f32x2 f0[4], f1[4];
        unpack8v(u0, f0); unpack8v(u1, f1);
        f32x2 p0 = fd2[0] * f0[0];
        f32x2 p1 = fd2[0] * f1[0];
#pragma unroll
        for (int k = 1; k < 4; ++k) { p0 += fd2[k] * f0[k]; p1 += fd2[k] * f1[k]; }
        float q0 = p0.x + p0.y;
        float q1 = p1.x + p1.y;
        q0 += __shfl_xor(q0, 1); q1 += __shfl_xor(q1, 1);
        q0 += __shfl_xor(q0, 2); q1 += __shfl_xor(q1, 2);
        q0 += __shfl_xor(q0, 4); q1 += __shfl_xor(q1, 4);
        float w0 = __expf(q0 * 0.125f);
        float w1 = __expf(q1 * 0.125f);
        f32x2 W0 = (f32x2){w0, w0}, W1 = (f32x2){w1, w1};
#pragma unroll
        for (int k = 0; k < 4; ++k) {
            acc2[k] += W0 * f0[k];
            acc2[k] += W1 * f1[k];
        }
        l += w0 + w1;
    }
    if (base < e1) {
        int s = csr_src[base];
        uint4 u = *(const uint4*)(fb + ((unsigned)s << 7) + loff);
        f32x2 fv[4];
        unpack8v(u, fv);
        f32x2 p = fd2[0] * fv[0];
#pragma unroll
        for (int k = 1; k < 4; ++k) p += fd2[k] * fv[k];
        float q = p.x + p.y;
        q += __shfl_xor(q, 1);
        q += __shfl_xor(q, 2);
        q += __shfl_xor(q, 4);
        float w = __expf(q * 0.125f);
        f32x2 W = (f32x2){w, w};
#pragma unroll
        for (int k = 0; k < 4; ++k) acc2[k] += W * fv[k];
        l += w;
    }
    float rcp = 1.f / fmaxf(l, 1e-9f);
    float v[8];
#pragma unroll
    for (int k = 0; k < 4; ++k) {
        v[2 * k]     = acc2[k].x * rcp;
        v[2 * k + 1] = acc2[k].y * rcp;
    }
    if (f) {
        float* op = (float*)out + ((size_t)dstn << 6) + (gl << 3);
        *(float4*)(op)     = (float4){v[0], v[1], v[2], v[3]};
        *(float4*)(op + 4) = (float4){v[4], v[5], v[6], v[7]};
    } else {
        uint4 pk;
        pk.x = (unsigned)f32_to_bf16_raw(v[0]) | ((unsigned)f32_to_bf16_raw(v[1]) << 16);
        pk.y = (unsigned)f32_to_bf16_raw(v[2]) | ((unsigned)f32_to_bf16_raw(v[3]) << 16);
        pk.z = (unsigned)f32_to_bf16_raw(v[4]) | ((unsigned)f32_to_bf16_raw(v[5]) << 16);
        pk.w = (unsigned)f32_to_bf16_raw(v[6]) | ((unsigned)f32_to_bf16_raw(v[7]) << 16);
        *(uint4*)((unsigned short*)out + ((size_t)dstn << 6) + (gl << 3)) = pk;
    }
}

extern "C" void kernel_launch(void* const* d_in, const int* in_sizes, int n_in,
                              void* d_out, int out_size, void* d_ws, size_t ws_size,
                              hipStream_t stream) {
    const void* h  = d_in[0];
    const void* W1 = d_in[1];
    const void* W2 = d_in[2];
    const int* src = (const int*)d_in[3];
    const int* dst = (const int*)d_in[4];

    float* ws = (float*)d_ws;
    // Layout (4-byte words), peak ~45.5 MB.
    unsigned short* feat1 = (unsigned short*)ws;
    unsigned short* agg1e = (unsigned short*)(ws + 3200000);
    unsigned short* feat2 = (unsigned short*)ws;      // after feat1 dead
    unsigned* inter       = (unsigned*)(ws + 6400000);
    int*   csr_src        = (int*)(ws + 9600000);
    int*   start          = (int*)(ws + 11200000);
    int*   flag           = (int*)(ws + 11330000);
    int*   bcnt           = (int*)(ws + 11331000);
    int*   bbase          = (int*)(ws + 11332000);
    int*   bcur           = (int*)(ws + 11333000);
    unsigned short* W1T   = (unsigned short*)(ws + 11340000);
    unsigned short* W2T   = (unsigned short*)(ws + 11350000);

    detect_dtype_kernel<<<1, 256, 0, stream>>>((const unsigned short*)W1, flag, bcnt);
    prep_kernel<<<12, 256, 0, stream>>>(W1, W2, W1T, W2T, flag);

    // ---- binned CSR build (by dst), storing src ids ----
    bucket_count_kernel<<<NB_A, 256, 0, stream>>>(dst, bcnt, N_EDGES);
    bucket_scan_kernel<<<1, 128, 0, stream>>>(bcnt, bbase, bcur);
    binA_kernel<<<NB_A, 256, 0, stream>>>(src, dst, bcur, inter, N_EDGES);
    binB_kernel<<<NBUCK, 256, 0, stream>>>(inter, bbase, csr_src, start, N_NODES, N_EDGES);

    gemm1_mfma_kernel<<<(N_NODES + 63) / 64, 256, 0, stream>>>(h, W1T, feat1, N_NODES, flag);
    // 8 dsts per wave -> ceil(N/8) waves, 4 waves per block
    int nwaves = (N_NODES + 7) / 8;
    gat1_kernel<<<(nwaves + 3) / 4, 256, 0, stream>>>(feat1, csr_src, start, agg1e, N_NODES);
    gemm2_mfma_kernel<<<(N_NODES + 63) / 64, 256, 0, stream>>>(agg1e, W2T, feat2, N_NODES);
    gat2_kernel<<<(nwaves + 3) / 4, 256, 0, stream>>>(feat2, csr_src, start, d_out, N_NODES, flag);
}